// Round 19
// baseline (46.629 us; speedup 1.0000x reference)
//
#include <hip/hip_runtime.h>

// SigLoss: signature kernel PDE, loss = mean_a( K(X,X) + K(Y,Y) - 2 K(X,Y) ).
// A=256, L=256, D=32. One 64-lane wave per (pair,a) problem.
// R19: AFFINE-PIPELINED SCAN. R13-R18 all land at ~412cyc/row with only ~90
// issue -> the per-row dependent chain (E -> kp -> c(kn DPP) -> L/T -> 6 DPP
// -> E, ~11 deps) is the wall. The row map is affine in E: with u_s = 1 +
// L_{s-1}, c_s = E(1+m_s) + (u_{s+1} + u_s m_s), so T_{r+1} = A*E_r + Q with
// (A,Q) prepared BEFORE E_r resolves, and kn = 1+E+T is in-lane (no DPP).
// Chain/row = fma + 6 DPP + sub = 8 deps; all prep (~23 VALU) + 1 MFMA tile
// + LDS reads run in the DPP shadow. kp never materialized (K = 1+E+L2).
// Tiles of block p interleave with scan rows of block p-1 (tile k, row k);
// boundary prep for row 16p reads block p row 0 after tile 15 (same-wave DS
// order). B-frags in regs (R18), incD double-buffered.

typedef _Float16 half8 __attribute__((ext_vector_type(8)));
typedef float f32x4_t __attribute__((ext_vector_type(4)));

#define DPP_ADD(v, ctrl, rmask)                                               \
    ((v) + __int_as_float(__builtin_amdgcn_update_dpp(                        \
               0, __float_as_int(v), (ctrl), (rmask), 0xF, true)))

#define INV2048 4.8828125e-4f

__global__ __launch_bounds__(64)
__attribute__((amdgpu_waves_per_eu(1, 1)))
void sig_pde(const float* __restrict__ X,
             const float* __restrict__ Y,
             float* __restrict__ partial) {
    const int bid = blockIdx.x;
    const int p = bid >> 8;          // 0=xx, 1=yy, 2=xy
    const int a = bid & 255;
    const float* __restrict__ U = (p == 1) ? Y : X;   // rows (i)
    const float* __restrict__ V = (p == 0) ? X : Y;   // cols (j)
    U += (size_t)a * 256 * 32;
    V += (size_t)a * 256 * 32;
    const int lane = threadIdx.x;
    const int m16 = lane & 15;
    const int g2 = (lane >> 4) * 2;

    __shared__ __attribute__((aligned(16))) float incD[2][16 * 260]; // 33.3 KB

    const float4* U4 = (const float4*)U;
    const float4* V4 = (const float4*)V;

    // ---- B fragments dY hi/lo in registers (128 VGPR), R18-verified ----
    half8 bh[16], bl[16];
#pragma unroll
    for (int t = 0; t < 16; ++t) {
        int col = t * 16 + m16;
        int cp = (col + 1 < 256) ? col + 1 : 255;
        float4 lo0 = V4[col * 8 + g2], lo1 = V4[col * 8 + g2 + 1];
        float4 hi0 = V4[cp * 8 + g2],  hi1 = V4[cp * 8 + g2 + 1];
        float d[8] = {hi0.x - lo0.x, hi0.y - lo0.y, hi0.z - lo0.z, hi0.w - lo0.w,
                      hi1.x - lo1.x, hi1.y - lo1.y, hi1.z - lo1.z, hi1.w - lo1.w};
#pragma unroll
        for (int i = 0; i < 8; ++i) {
            _Float16 h = (_Float16)d[i];
            bh[t][i] = h;
            bl[t][i] = (_Float16)((d[i] - (float)h) * 2048.0f);
        }
    }

    auto loadA = [&](int blk, float4 (&dst)[4]) {
        int r0 = blk * 16 + m16;
        int r1 = (r0 + 1 < 256) ? r0 + 1 : 255;
        dst[0] = U4[r0 * 8 + g2];
        dst[1] = U4[r0 * 8 + g2 + 1];
        dst[2] = U4[r1 * 8 + g2];
        dst[3] = U4[r1 * 8 + g2 + 1];
    };
    auto makeAhAl = [&](const float4 (&src)[4], half8& ah, half8& al) {
        float d[8] = {src[2].x - src[0].x, src[2].y - src[0].y,
                      src[2].z - src[0].z, src[2].w - src[0].w,
                      src[3].x - src[1].x, src[3].y - src[1].y,
                      src[3].z - src[1].z, src[3].w - src[1].w};
#pragma unroll
        for (int i = 0; i < 8; ++i) {
            _Float16 h = (_Float16)d[i];
            ah[i] = h;
            al[i] = (_Float16)((d[i] - (float)h) * 2048.0f);
        }
    };

    const f32x4_t zero4 = {0.0f, 0.0f, 0.0f, 0.0f};
    const f32x4_t mone4 = {-1.0f, -1.0f, -1.0f, -1.0f};
    const int rb = (lane >> 4) << 2;

    auto tile = [&](int t, const half8& ah, const half8& al,
                    float* __restrict__ buf) {
        f32x4_t acc2 =
            __builtin_amdgcn_mfma_f32_16x16x32_f16(ah, bl[t], zero4, 0, 0, 0);
        acc2 = __builtin_amdgcn_mfma_f32_16x16x32_f16(al, bh[t], acc2, 0, 0, 0);
        f32x4_t acc1 =
            __builtin_amdgcn_mfma_f32_16x16x32_f16(ah, bh[t], mone4, 0, 0, 0);
        int cc = t * 16 + m16;
        buf[(rb + 0) * 260 + cc] = fmaf(acc2[0], INV2048, acc1[0]);
        buf[(rb + 1) * 260 + cc] = fmaf(acc2[1], INV2048, acc1[1]);
        buf[(rb + 2) * 260 + cc] = fmaf(acc2[2], INV2048, acc1[2]);
        buf[(rb + 3) * 260 + cc] = fmaf(acc2[3], INV2048, acc1[3]);
    };

    // ---- Affine scan state ----
    float E = 0.0f;                       // exclusive prefix of previous row
    float A_, Q_, aL0, aL1, aL2, qL0, qL1, qL2;
    float lastL2 = 0.0f;

    // prep coefficients for the NEXT row from its m values (m = inc-1) and
    // the u's derived from the current row's locals.
    auto prep = [&](float4 m, float u1, float u2, float u3, float u4) {
        float a0 = 1.0f + m.x, a1 = 1.0f + m.y;
        float a2 = 1.0f + m.z, a3 = 1.0f + m.w;
        float q0 = u1 + m.x;              // u0 == 1 always
        float q1 = fmaf(u1, m.y, u2);
        float q2 = fmaf(u2, m.z, u3);
        float q3 = fmaf(u3, m.w, u4);
        if (lane == 63) { a3 = 0.0f; q3 = 0.0f; }   // c[255] doesn't exist
        aL0 = a0; aL1 = a0 + a1; aL2 = aL1 + a2; A_ = aL2 + a3;
        qL0 = q0; qL1 = q0 + q1; qL2 = qL1 + q2; Q_ = qL2 + q3;
    };

    // ---- Phase 0: produce block 0, prep row 0 (E=0, all u's = 1) ----
    float4 Abuf[4];
    loadA(0, Abuf);
    half8 ah, al;
    makeAhAl(Abuf, ah, al);
#pragma unroll
    for (int t = 0; t < 16; ++t) tile(t, ah, al, incD[0]);
    loadA(1, Abuf);
    {
        const float4* rp0 = (const float4*)incD[0];
        float4 m0 = rp0[0 * 65 + lane];   // after tiles: same-wave DS order
        prep(m0, 1.0f, 1.0f, 1.0f, 1.0f);
    }

    // ---- Phases 1..15: scan block pp-1 (16 rows) | produce block pp ----
#pragma clang loop unroll(disable)
    for (int pp = 1; pp < 16; ++pp) {
        const float4* rp = (const float4*)incD[(pp - 1) & 1];
        float* wb = incD[pp & 1];
        makeAhAl(Abuf, ah, al);
        if (pp + 1 < 16) loadA(pp + 1, Abuf);
        float4 w[4];
        w[0] = rp[1 * 65 + lane]; w[1] = rp[2 * 65 + lane];
        w[2] = rp[3 * 65 + lane]; w[3] = rp[4 * 65 + lane];
#pragma unroll
        for (int k = 0; k < 16; ++k) {
            tile(k, ah, al, wb);
            // chain: T = A*E + Q -> 6-DPP scan -> E
            float T = fmaf(E, A_, Q_);
            float S = T;
            S = DPP_ADD(S, 0x111, 0xF);
            S = DPP_ADD(S, 0x112, 0xF);
            S = DPP_ADD(S, 0x114, 0xF);
            S = DPP_ADD(S, 0x118, 0xF);
            S = DPP_ADD(S, 0x142, 0xA);
            S = DPP_ADD(S, 0x143, 0xC);
            // shadow: locals of this row (use OLD E), u's, prep next row
            float L0 = fmaf(E, aL0, qL0);
            float L1 = fmaf(E, aL1, qL1);
            float L2 = fmaf(E, aL2, qL2);
            float u1 = 1.0f + L0, u2 = 1.0f + L1;
            float u3 = 1.0f + L2, u4 = 1.0f + T;
            float4 m;
            if (k < 15) {
                m = w[k & 3];
                if (k <= 10) w[k & 3] = rp[(k + 5) * 65 + lane];
            } else {
                m = ((const float4*)wb)[0 * 65 + lane];  // block pp row 0
            }
            prep(m, u1, u2, u3, u4);
            lastL2 = L2;
            E = S - T;
        }
    }

    // ---- Final phase: scan block 15, rows 0..14 (global 240..254) ----
    {
        const float4* rp = (const float4*)incD[1];
        float4 w[4];
        w[0] = rp[1 * 65 + lane]; w[1] = rp[2 * 65 + lane];
        w[2] = rp[3 * 65 + lane]; w[3] = rp[4 * 65 + lane];
#pragma unroll
        for (int k = 0; k < 15; ++k) {
            float T = fmaf(E, A_, Q_);
            float S = T;
            S = DPP_ADD(S, 0x111, 0xF);
            S = DPP_ADD(S, 0x112, 0xF);
            S = DPP_ADD(S, 0x114, 0xF);
            S = DPP_ADD(S, 0x118, 0xF);
            S = DPP_ADD(S, 0x142, 0xA);
            S = DPP_ADD(S, 0x143, 0xC);
            float L0 = fmaf(E, aL0, qL0);
            float L1 = fmaf(E, aL1, qL1);
            float L2 = fmaf(E, aL2, qL2);
            if (k < 14) {
                float u1 = 1.0f + L0, u2 = 1.0f + L1;
                float u3 = 1.0f + L2, u4 = 1.0f + T;
                float4 m = w[k & 3];
                if (k <= 9) w[k & 3] = rp[(k + 5) * 65 + lane];
                prep(m, u1, u2, u3, u4);
            }
            lastL2 = L2;
            E = S - T;
        }
    }

    if (lane == 63) {
        // K[255][255] = 1 + E_254 + L2_254
        partial[bid] = (p == 2 ? -2.0f : 1.0f) * (1.0f + E + lastL2);
    }
}

__global__ __launch_bounds__(256) void sig_reduce(const float* __restrict__ partial,
                                                  float* __restrict__ out) {
    const int t = threadIdx.x;
    float v = partial[t] + partial[t + 256] + partial[t + 512];
#pragma unroll
    for (int ofs = 32; ofs > 0; ofs >>= 1) v += __shfl_down(v, ofs);
    __shared__ float ws[4];
    if ((t & 63) == 0) ws[t >> 6] = v;
    __syncthreads();
    if (t == 0) out[0] = (ws[0] + ws[1] + ws[2] + ws[3]) * (1.0f / 256.0f);
}

extern "C" void kernel_launch(void* const* d_in, const int* in_sizes, int n_in,
                              void* d_out, int out_size, void* d_ws, size_t ws_size,
                              hipStream_t stream) {
    const float* X = (const float*)d_in[0];
    const float* Y = (const float*)d_in[1];
    float* partial = (float*)d_ws;       // 768 floats
    sig_pde<<<dim3(768), dim3(64), 0, stream>>>(X, Y, partial);
    sig_reduce<<<dim3(1), dim3(256), 0, stream>>>(partial, (float*)d_out);
}